// Round 1
// baseline (743.091 us; speedup 1.0000x reference)
//
#include <hip/hip_runtime.h>
#include <hip/hip_bf16.h>

#define NN 50000
#define HD 128
#define NL 4
#define BN_EPS 1e-5f

typedef __attribute__((ext_vector_type(8))) short short8;
typedef __attribute__((ext_vector_type(4))) float f32x4;

__device__ inline ushort f2bf(float f){
  uint u = __float_as_uint(f);
  uint r = (u + 0x7fffu + ((u >> 16) & 1u)) >> 16;
  return (ushort)r;
}
__device__ inline float bflo(uint u){ return __uint_as_float(u << 16); }
__device__ inline float bfhi(uint u){ return __uint_as_float(u & 0xffff0000u); }

// ---------------- cast fp32 -> bf16, vectorized x4 ----------------
__global__ void cast_f32_bf16x4(const float* __restrict__ in, ushort* __restrict__ out, int n4){
  int i = blockIdx.x * blockDim.x + threadIdx.x;
  int stride = gridDim.x * blockDim.x;
  const float4* in4 = (const float4*)in;
  for (; i < n4; i += stride){
    float4 v = in4[i];
    ushort4 r;
    r.x = f2bf(v.x); r.y = f2bf(v.y); r.z = f2bf(v.z); r.w = f2bf(v.w);
    *(ushort4*)(out + i * 4) = r;
  }
}

// ---------------- CSR build ----------------
__global__ void hist_kernel(const int* __restrict__ dst, int* __restrict__ deg, int E){
  int e = blockIdx.x * 256 + threadIdx.x;
  if (e < E) atomicAdd(&deg[dst[e]], 1);
}

__global__ void scan_kernel(const int* __restrict__ deg, int* __restrict__ off, int n){
  __shared__ int sums[1024];
  int t = threadIdx.x;
  int C = (n + 1023) >> 10;
  int b = t * C;
  int e = b + C < n ? b + C : n;
  int local = 0;
  for (int i = b; i < e; ++i) local += deg[i];
  sums[t] = local;
  __syncthreads();
  for (int ofs = 1; ofs < 1024; ofs <<= 1){
    int v = sums[t];
    int add = (t >= ofs) ? sums[t - ofs] : 0;
    __syncthreads();
    sums[t] = v + add;
    __syncthreads();
  }
  int run = (t == 0) ? 0 : sums[t - 1];
  for (int i = b; i < e; ++i){ off[i] = run; run += deg[i]; }
  if (t == 1023) off[n] = run;
}

__global__ void fill_kernel(const int* __restrict__ src, const int* __restrict__ dst,
                            const int* __restrict__ off, int* __restrict__ cur,
                            int* __restrict__ csrc, int E){
  int e = blockIdx.x * 256 + threadIdx.x;
  if (e < E){
    int d = dst[e];
    int p = atomicAdd(&cur[d], 1);
    csrc[off[d] + p] = src[e];
  }
}

// ---------------- aggregation: h[v] = x[v] + sum_{e:dst=v} x[src[e]] ----------------
// one wave per node; lane handles 2 columns (one uint = 2 bf16)
__global__ __launch_bounds__(256) void agg_kernel(const ushort* __restrict__ xb,
                                                  const int* __restrict__ off,
                                                  const int* __restrict__ csrc,
                                                  ushort* __restrict__ h){
  int node = blockIdx.x * 4 + (threadIdx.x >> 6);
  int lane = threadIdx.x & 63;
  const uint* xr = (const uint*)xb;   // 64 uints per row
  uint self = xr[node * 64 + lane];
  float ax = bflo(self), ay = bfhi(self);
  int s = off[node], e = off[node + 1];
  int j = s;
  for (; j + 4 <= e; j += 4){
    int u0 = csrc[j], u1 = csrc[j+1], u2 = csrc[j+2], u3 = csrc[j+3];
    uint v0 = xr[u0 * 64 + lane];
    uint v1 = xr[u1 * 64 + lane];
    uint v2 = xr[u2 * 64 + lane];
    uint v3 = xr[u3 * 64 + lane];
    ax += bflo(v0) + bflo(v1) + bflo(v2) + bflo(v3);
    ay += bfhi(v0) + bfhi(v1) + bfhi(v2) + bfhi(v3);
  }
  for (; j < e; ++j){
    uint v = xr[csrc[j] * 64 + lane];
    ax += bflo(v); ay += bfhi(v);
  }
  uint o = (uint)f2bf(ax) | ((uint)f2bf(ay) << 16);
  ((uint*)h)[node * 64 + lane] = o;
}

// ---------------- GEMM: Y[N,128] = A[N,128](bf16) @ W[128,128]^T(bf16) + bias ----------------
// per block: 4 waves x 2 row-tiles of 16 = 128 rows; W staged in LDS (padded).
// optional fused column sum/sumsq atomics into stats[0..127]=sum, [128..255]=sumsq.
__global__ __launch_bounds__(256) void gemm_kernel(const ushort* __restrict__ A,
                                                   const ushort* __restrict__ W,
                                                   const float* __restrict__ bias,
                                                   float* __restrict__ Y,
                                                   float* __restrict__ stats,
                                                   int nTiles){
  __shared__ uint4 w4[128 * 17];   // row stride 17 uint4 = 136 bf16 (pad 8) -> 2-way-max banks
  __shared__ float ssum[128];
  __shared__ float ssq[128];
  const uint4* Wg = (const uint4*)W;
  for (int c = threadIdx.x; c < 2048; c += 256){
    w4[(c >> 4) * 17 + (c & 15)] = Wg[c];
  }
  if (threadIdx.x < 128){ ssum[threadIdx.x] = 0.f; ssq[threadIdx.x] = 0.f; }
  __syncthreads();

  int wave = threadIdx.x >> 6;
  int lane = threadIdx.x & 63;
  int m = lane & 15, q = lane >> 4;
  int t0 = blockIdx.x * 8 + wave * 2;
  int t1 = t0 + 1;
  bool v0 = t0 < nTiles, v1 = t1 < nTiles;
  const uint4* A4 = (const uint4*)A;

  f32x4 acc0[8], acc1[8];
#pragma unroll
  for (int i = 0; i < 8; ++i){ acc0[i] = (f32x4)0.f; acc1[i] = (f32x4)0.f; }

#pragma unroll
  for (int kt = 0; kt < 4; ++kt){
    short8 a0 = (short8)0, a1 = (short8)0;
    if (v0){ uint4 t = A4[(t0 * 16 + m) * 16 + kt * 4 + q]; a0 = *(short8*)&t; }
    if (v1){ uint4 t = A4[(t1 * 16 + m) * 16 + kt * 4 + q]; a1 = *(short8*)&t; }
#pragma unroll
    for (int to = 0; to < 8; ++to){
      uint4 bw = w4[(to * 16 + m) * 17 + kt * 4 + q];
      short8 bb = *(short8*)&bw;
      acc0[to] = __builtin_amdgcn_mfma_f32_16x16x32_bf16(a0, bb, acc0[to], 0, 0, 0);
      acc1[to] = __builtin_amdgcn_mfma_f32_16x16x32_bf16(a1, bb, acc1[to], 0, 0, 0);
    }
  }

  bool dost = (stats != nullptr);
#pragma unroll
  for (int to = 0; to < 8; ++to){
    int col = to * 16 + m;
    float bc = bias[col];
    if (v0){
      float ls = 0.f, lq = 0.f;
#pragma unroll
      for (int r = 0; r < 4; ++r){
        float v = acc0[to][r] + bc;
        Y[(t0 * 16 + q * 4 + r) * 128 + col] = v;
        ls += v; lq += v * v;
      }
      if (dost){ atomicAdd(&ssum[col], ls); atomicAdd(&ssq[col], lq); }
    }
    if (v1){
      float ls = 0.f, lq = 0.f;
#pragma unroll
      for (int r = 0; r < 4; ++r){
        float v = acc1[to][r] + bc;
        Y[(t1 * 16 + q * 4 + r) * 128 + col] = v;
        ls += v; lq += v * v;
      }
      if (dost){ atomicAdd(&ssum[col], ls); atomicAdd(&ssq[col], lq); }
    }
  }
  __syncthreads();
  if (dost && threadIdx.x < 128){
    atomicAdd(&stats[threadIdx.x], ssum[threadIdx.x]);
    atomicAdd(&stats[128 + threadIdx.x], ssq[threadIdx.x]);
  }
}

// ---------------- per-column BN params ----------------
// bn1: consumer computes relu(y*s + t)
__global__ void stats1_kernel(const float* __restrict__ st, const float* __restrict__ g,
                              const float* __restrict__ b, float* __restrict__ p){
  int c = threadIdx.x;
  const float invN = 1.f / (float)NN;
  float mu = st[c] * invN;
  float var = st[128 + c] * invN - mu * mu;
  var = fmaxf(var, 0.f);
  float s = g[c] * rsqrtf(var + BN_EPS);
  p[c] = s;
  p[128 + c] = b[c] - mu * s;
}

// bn3(bn2(q)) composed: mean(bn2 out)=b2 exactly, var=g2^2*var/(var+eps)
// => relu(q*S + T), S = inv2*g2*inv3*g3, T = b3 - mu*S  (b2 cancels exactly)
__global__ void stats23_kernel(const float* __restrict__ st, const float* __restrict__ g2,
                               const float* __restrict__ g3, const float* __restrict__ b3,
                               float* __restrict__ p){
  int c = threadIdx.x;
  const float invN = 1.f / (float)NN;
  float mu = st[c] * invN;
  float var = st[128 + c] * invN - mu * mu;
  var = fmaxf(var, 0.f);
  float inv2 = rsqrtf(var + BN_EPS);
  float tt = g2[c] * inv2;
  float varv = tt * tt * var;
  float inv3 = rsqrtf(varv + BN_EPS);
  float S = tt * inv3 * g3[c];
  p[c] = S;
  p[128 + c] = b3[c] - mu * S;
}

// ---------------- apply relu(y*s+t), cast to bf16 ----------------
__global__ void transform_kernel(const float* __restrict__ y, const float* __restrict__ p,
                                 ushort* __restrict__ ob, int n4){
  int i = blockIdx.x * blockDim.x + threadIdx.x;
  int stride = gridDim.x * blockDim.x;
  const float4* y4 = (const float4*)y;
  for (; i < n4; i += stride){
    int col = (i * 4) & 127;
    float4 v = y4[i];
    float4 s = *(const float4*)&p[col];
    float4 t = *(const float4*)&p[128 + col];
    float r0 = fmaxf(v.x * s.x + t.x, 0.f);
    float r1 = fmaxf(v.y * s.y + t.y, 0.f);
    float r2 = fmaxf(v.z * s.z + t.z, 0.f);
    float r3 = fmaxf(v.w * s.w + t.w, 0.f);
    ushort4 r;
    r.x = f2bf(r0); r.y = f2bf(r1); r.z = f2bf(r2); r.w = f2bf(r3);
    *(ushort4*)(ob + i * 4) = r;
  }
}

extern "C" void kernel_launch(void* const* d_in, const int* in_sizes, int n_in,
                              void* d_out, int out_size, void* d_ws, size_t ws_size,
                              hipStream_t stream) {
  const float* x     = (const float*)d_in[0];
  const int*   ei    = (const int*)d_in[1];
  const float* fc1_w = (const float*)d_in[2];
  const float* fc1_b = (const float*)d_in[3];
  const float* bn1_g = (const float*)d_in[4];
  const float* bn1_b = (const float*)d_in[5];
  const float* fc2_w = (const float*)d_in[6];
  const float* fc2_b = (const float*)d_in[7];
  const float* bn2_g = (const float*)d_in[8];
  const float* bn3_g = (const float*)d_in[10];
  const float* bn3_b = (const float*)d_in[11];
  const float* fc_w  = (const float*)d_in[12];
  const float* fc_b  = (const float*)d_in[13];

  int E = in_sizes[1] / 2;
  const int* srcp = ei;
  const int* dstp = ei + E;

  char* ws = (char*)d_ws;
  int*    off    = (int*)(ws + 0);            // (N+1) ints
  int*    deg    = (int*)(ws + 200064);       // N ints
  int*    cur    = (int*)(ws + 400128);       // N ints
  int*    csrc   = (int*)(ws + 600192);       // E ints
  ushort* wb     = (ushort*)(ws + 3800192);   // 147456 bf16 (fc1_w x4 | fc2_w x4 | fc_w)
  float*  stats  = (float*)(ws + 4095104);    // 8 slices x 256
  float*  params = (float*)(ws + 4103296);    // 8 slices x 256
  ushort* xb     = (ushort*)(ws + 4111488);   // N*128 bf16
  ushort* hb     = (ushort*)(ws + 16911488);  // N*128 bf16 (also reused as p)
  float*  y      = (float*)(ws + 29711488);   // N*128 f32

  hipMemsetAsync(deg, 0, 400128, stream);     // deg + cur
  hipMemsetAsync(stats, 0, 8192, stream);

  cast_f32_bf16x4<<<2048, 256, 0, stream>>>(x, xb, NN * HD / 4);
  cast_f32_bf16x4<<<64, 256, 0, stream>>>(fc1_w, wb, NL * HD * HD / 4);
  cast_f32_bf16x4<<<64, 256, 0, stream>>>(fc2_w, wb + 65536, NL * HD * HD / 4);
  cast_f32_bf16x4<<<16, 256, 0, stream>>>(fc_w, wb + 131072, HD * HD / 4);

  int eb = (E + 255) / 256;
  hist_kernel<<<eb, 256, 0, stream>>>(dstp, deg, E);
  scan_kernel<<<1, 1024, 0, stream>>>(deg, off, NN);
  fill_kernel<<<eb, 256, 0, stream>>>(srcp, dstp, off, cur, csrc, E);

  const int nT = NN / 16;         // 3125 row tiles
  const int gb = (nT + 7) / 8;    // 391 blocks

  for (int i = 0; i < NL; ++i){
    agg_kernel<<<NN / 4, 256, 0, stream>>>(xb, off, csrc, hb);
    gemm_kernel<<<gb, 256, 0, stream>>>(hb, wb + i * 16384, fc1_b + i * 128,
                                        y, stats + (2 * i) * 256, nT);
    stats1_kernel<<<1, 128, 0, stream>>>(stats + (2 * i) * 256, bn1_g + i * 128,
                                         bn1_b + i * 128, params + (2 * i) * 256);
    transform_kernel<<<2048, 256, 0, stream>>>(y, params + (2 * i) * 256, hb, NN * HD / 4);
    gemm_kernel<<<gb, 256, 0, stream>>>(hb, wb + 65536 + i * 16384, fc2_b + i * 128,
                                        y, stats + (2 * i + 1) * 256, nT);
    stats23_kernel<<<1, 128, 0, stream>>>(stats + (2 * i + 1) * 256, bn2_g + i * 128,
                                          bn3_g + i * 128, bn3_b + i * 128,
                                          params + (2 * i + 1) * 256);
    transform_kernel<<<2048, 256, 0, stream>>>(y, params + (2 * i + 1) * 256, xb, NN * HD / 4);
  }

  gemm_kernel<<<gb, 256, 0, stream>>>(xb, wb + 131072, fc_b, (float*)d_out, nullptr, nT);
}

// Round 2
// 674.408 us; speedup vs baseline: 1.1018x; 1.1018x over previous
//
#include <hip/hip_runtime.h>
#include <hip/hip_bf16.h>

#define NN 50000
#define HD 128
#define NL 4
#define BN_EPS 1e-5f

typedef __attribute__((ext_vector_type(8))) short short8;
typedef __attribute__((ext_vector_type(4))) float f32x4;

__device__ inline ushort f2bf(float f){
  uint u = __float_as_uint(f);
  uint r = (u + 0x7fffu + ((u >> 16) & 1u)) >> 16;
  return (ushort)r;
}
__device__ inline float bflo(uint u){ return __uint_as_float(u << 16); }
__device__ inline float bfhi(uint u){ return __uint_as_float(u & 0xffff0000u); }

// ---------------- cast fp32 -> bf16, vectorized x4 ----------------
__global__ void cast_f32_bf16x4(const float* __restrict__ in, ushort* __restrict__ out, int n4){
  int i = blockIdx.x * blockDim.x + threadIdx.x;
  int stride = gridDim.x * blockDim.x;
  const float4* in4 = (const float4*)in;
  for (; i < n4; i += stride){
    float4 v = in4[i];
    ushort4 r;
    r.x = f2bf(v.x); r.y = f2bf(v.y); r.z = f2bf(v.z); r.w = f2bf(v.w);
    *(ushort4*)(out + i * 4) = r;
  }
}

// ---------------- CSR build ----------------
__global__ void hist_kernel(const int* __restrict__ dst, int* __restrict__ deg, int E){
  int e = blockIdx.x * 256 + threadIdx.x;
  if (e < E) atomicAdd(&deg[dst[e]], 1);
}

// device-wide exclusive scan, 3 phases
__global__ void scan1_kernel(const int* __restrict__ deg, int* __restrict__ incl,
                             int* __restrict__ bsum, int n){
  __shared__ int tmp[1024];
  int gid = blockIdx.x * 1024 + threadIdx.x;
  int v = (gid < n) ? deg[gid] : 0;
  tmp[threadIdx.x] = v;
  __syncthreads();
  for (int ofs = 1; ofs < 1024; ofs <<= 1){
    int t = tmp[threadIdx.x];
    int a = (threadIdx.x >= ofs) ? tmp[threadIdx.x - ofs] : 0;
    __syncthreads();
    tmp[threadIdx.x] = t + a;
    __syncthreads();
  }
  if (gid < n) incl[gid] = tmp[threadIdx.x];
  if (threadIdx.x == 1023) bsum[blockIdx.x] = tmp[1023];
}

__global__ void scan2_kernel(const int* __restrict__ bsum, int* __restrict__ base,
                             int* __restrict__ off, int nb, int n){
  if (threadIdx.x == 0){
    int run = 0;
    for (int i = 0; i < nb; ++i){ base[i] = run; run += bsum[i]; }
    off[n] = run;
  }
}

__global__ void scan3_kernel(const int* __restrict__ deg, const int* __restrict__ incl,
                             const int* __restrict__ base, int* __restrict__ off, int n){
  int gid = blockIdx.x * 1024 + threadIdx.x;
  if (gid < n) off[gid] = incl[gid] - deg[gid] + base[blockIdx.x];
}

__global__ void fill_kernel(const int* __restrict__ src, const int* __restrict__ dst,
                            const int* __restrict__ off, int* __restrict__ cur,
                            int* __restrict__ csrc, int E){
  int e = blockIdx.x * 256 + threadIdx.x;
  if (e < E){
    int d = dst[e];
    int p = atomicAdd(&cur[d], 1);
    csrc[off[d] + p] = src[e];
  }
}

// ---------------- aggregation: h[v] = x[v] + sum_{e:dst=v} x[src[e]] ----------------
// one wave per node; lane handles 2 columns (one uint = 2 bf16)
__global__ __launch_bounds__(256) void agg_kernel(const ushort* __restrict__ xb,
                                                  const int* __restrict__ off,
                                                  const int* __restrict__ csrc,
                                                  ushort* __restrict__ h){
  int node = blockIdx.x * 4 + (threadIdx.x >> 6);
  int lane = threadIdx.x & 63;
  const uint* xr = (const uint*)xb;   // 64 uints per row
  uint self = xr[node * 64 + lane];
  float ax = bflo(self), ay = bfhi(self);
  int s = off[node], e = off[node + 1];
  int j = s;
  for (; j + 4 <= e; j += 4){
    int u0 = csrc[j], u1 = csrc[j+1], u2 = csrc[j+2], u3 = csrc[j+3];
    uint v0 = xr[u0 * 64 + lane];
    uint v1 = xr[u1 * 64 + lane];
    uint v2 = xr[u2 * 64 + lane];
    uint v3 = xr[u3 * 64 + lane];
    ax += bflo(v0) + bflo(v1) + bflo(v2) + bflo(v3);
    ay += bfhi(v0) + bfhi(v1) + bfhi(v2) + bfhi(v3);
  }
  for (; j < e; ++j){
    uint v = xr[csrc[j] * 64 + lane];
    ax += bflo(v); ay += bfhi(v);
  }
  uint o = (uint)f2bf(ax) | ((uint)f2bf(ay) << 16);
  ((uint*)h)[node * 64 + lane] = o;
}

// ---------------- GEMM: Y[N,128] = A[N,128](bf16) @ W[128,128]^T(bf16) + bias ----------------
__global__ __launch_bounds__(256) void gemm_kernel(const ushort* __restrict__ A,
                                                   const ushort* __restrict__ W,
                                                   const float* __restrict__ bias,
                                                   float* __restrict__ Y,
                                                   float* __restrict__ stats,
                                                   int nTiles){
  __shared__ uint4 w4[128 * 17];   // row stride 17 uint4 = 136 bf16 (pad 8)
  __shared__ float ssum[128];
  __shared__ float ssq[128];
  const uint4* Wg = (const uint4*)W;
  for (int c = threadIdx.x; c < 2048; c += 256){
    w4[(c >> 4) * 17 + (c & 15)] = Wg[c];
  }
  if (threadIdx.x < 128){ ssum[threadIdx.x] = 0.f; ssq[threadIdx.x] = 0.f; }
  __syncthreads();

  int wave = threadIdx.x >> 6;
  int lane = threadIdx.x & 63;
  int m = lane & 15, q = lane >> 4;
  int t0 = blockIdx.x * 8 + wave * 2;
  int t1 = t0 + 1;
  bool v0 = t0 < nTiles, v1 = t1 < nTiles;
  const uint4* A4 = (const uint4*)A;

  f32x4 acc0[8], acc1[8];
#pragma unroll
  for (int i = 0; i < 8; ++i){ acc0[i] = (f32x4)0.f; acc1[i] = (f32x4)0.f; }

#pragma unroll
  for (int kt = 0; kt < 4; ++kt){
    short8 a0 = (short8)0, a1 = (short8)0;
    if (v0){ uint4 t = A4[(t0 * 16 + m) * 16 + kt * 4 + q]; a0 = *(short8*)&t; }
    if (v1){ uint4 t = A4[(t1 * 16 + m) * 16 + kt * 4 + q]; a1 = *(short8*)&t; }
#pragma unroll
    for (int to = 0; to < 8; ++to){
      uint4 bw = w4[(to * 16 + m) * 17 + kt * 4 + q];
      short8 bb = *(short8*)&bw;
      acc0[to] = __builtin_amdgcn_mfma_f32_16x16x32_bf16(a0, bb, acc0[to], 0, 0, 0);
      acc1[to] = __builtin_amdgcn_mfma_f32_16x16x32_bf16(a1, bb, acc1[to], 0, 0, 0);
    }
  }

  bool dost = (stats != nullptr);
#pragma unroll
  for (int to = 0; to < 8; ++to){
    int col = to * 16 + m;
    float bc = bias[col];
    if (v0){
      float ls = 0.f, lq = 0.f;
#pragma unroll
      for (int r = 0; r < 4; ++r){
        float v = acc0[to][r] + bc;
        Y[(t0 * 16 + q * 4 + r) * 128 + col] = v;
        ls += v; lq += v * v;
      }
      if (dost){ atomicAdd(&ssum[col], ls); atomicAdd(&ssq[col], lq); }
    }
    if (v1){
      float ls = 0.f, lq = 0.f;
#pragma unroll
      for (int r = 0; r < 4; ++r){
        float v = acc1[to][r] + bc;
        Y[(t1 * 16 + q * 4 + r) * 128 + col] = v;
        ls += v; lq += v * v;
      }
      if (dost){ atomicAdd(&ssum[col], ls); atomicAdd(&ssq[col], lq); }
    }
  }
  __syncthreads();
  if (dost && threadIdx.x < 128){
    atomicAdd(&stats[threadIdx.x], ssum[threadIdx.x]);
    atomicAdd(&stats[128 + threadIdx.x], ssq[threadIdx.x]);
  }
}

// ---------------- per-column BN params ----------------
__global__ void stats1_kernel(const float* __restrict__ st, const float* __restrict__ g,
                              const float* __restrict__ b, float* __restrict__ p){
  int c = threadIdx.x;
  const float invN = 1.f / (float)NN;
  float mu = st[c] * invN;
  float var = st[128 + c] * invN - mu * mu;
  var = fmaxf(var, 0.f);
  float s = g[c] * rsqrtf(var + BN_EPS);
  p[c] = s;
  p[128 + c] = b[c] - mu * s;
}

// bn3(bn2(q)) composed: mean(bn2 out)=b2 exactly, var=g2^2*var/(var+eps)
__global__ void stats23_kernel(const float* __restrict__ st, const float* __restrict__ g2,
                               const float* __restrict__ g3, const float* __restrict__ b3,
                               float* __restrict__ p){
  int c = threadIdx.x;
  const float invN = 1.f / (float)NN;
  float mu = st[c] * invN;
  float var = st[128 + c] * invN - mu * mu;
  var = fmaxf(var, 0.f);
  float inv2 = rsqrtf(var + BN_EPS);
  float tt = g2[c] * inv2;
  float varv = tt * tt * var;
  float inv3 = rsqrtf(varv + BN_EPS);
  float S = tt * inv3 * g3[c];
  p[c] = S;
  p[128 + c] = b3[c] - mu * S;
}

// ---------------- apply relu(y*s+t), cast to bf16 ----------------
__global__ void transform_kernel(const float* __restrict__ y, const float* __restrict__ p,
                                 ushort* __restrict__ ob, int n4){
  int i = blockIdx.x * blockDim.x + threadIdx.x;
  int stride = gridDim.x * blockDim.x;
  const float4* y4 = (const float4*)y;
  for (; i < n4; i += stride){
    int col = (i * 4) & 127;
    float4 v = y4[i];
    float4 s = *(const float4*)&p[col];
    float4 t = *(const float4*)&p[128 + col];
    float r0 = fmaxf(v.x * s.x + t.x, 0.f);
    float r1 = fmaxf(v.y * s.y + t.y, 0.f);
    float r2 = fmaxf(v.z * s.z + t.z, 0.f);
    float r3 = fmaxf(v.w * s.w + t.w, 0.f);
    ushort4 r;
    r.x = f2bf(r0); r.y = f2bf(r1); r.z = f2bf(r2); r.w = f2bf(r3);
    *(ushort4*)(ob + i * 4) = r;
  }
}

extern "C" void kernel_launch(void* const* d_in, const int* in_sizes, int n_in,
                              void* d_out, int out_size, void* d_ws, size_t ws_size,
                              hipStream_t stream) {
  const float* x     = (const float*)d_in[0];
  const int*   ei    = (const int*)d_in[1];
  const float* fc1_w = (const float*)d_in[2];
  const float* fc1_b = (const float*)d_in[3];
  const float* bn1_g = (const float*)d_in[4];
  const float* bn1_b = (const float*)d_in[5];
  const float* fc2_w = (const float*)d_in[6];
  const float* fc2_b = (const float*)d_in[7];
  const float* bn2_g = (const float*)d_in[8];
  const float* bn3_g = (const float*)d_in[10];
  const float* bn3_b = (const float*)d_in[11];
  const float* fc_w  = (const float*)d_in[12];
  const float* fc_b  = (const float*)d_in[13];

  int E = in_sizes[1] / 2;
  const int* srcp = ei;
  const int* dstp = ei + E;

  char* ws = (char*)d_ws;
  int*    off    = (int*)(ws + 0);            // (N+1) ints
  int*    deg    = (int*)(ws + 200064);       // N ints
  int*    cur    = (int*)(ws + 400128);       // N ints
  int*    csrc   = (int*)(ws + 600192);       // E ints (aliased as scan scratch `incl` pre-fill)
  ushort* wb     = (ushort*)(ws + 3800192);   // 147456 bf16 (fc1_w x4 | fc2_w x4 | fc_w)
  float*  stats  = (float*)(ws + 4095104);    // 8 slices x 256
  float*  params = (float*)(ws + 4103296);    // 8 slices x 256 (aliased as bsum/base pre-use)
  ushort* xb     = (ushort*)(ws + 4111488);   // N*128 bf16
  ushort* hb     = (ushort*)(ws + 16911488);  // N*128 bf16
  float*  y      = (float*)(ws + 29711488);   // N*128 f32

  int* incl = csrc;                 // dead before fill_kernel writes csrc
  int* bsum = (int*)params;         // dead before stats kernels write params
  int* base = (int*)params + 64;

  hipMemsetAsync(deg, 0, 400128, stream);     // deg + cur
  hipMemsetAsync(stats, 0, 8192, stream);

  cast_f32_bf16x4<<<2048, 256, 0, stream>>>(x, xb, NN * HD / 4);
  cast_f32_bf16x4<<<64, 256, 0, stream>>>(fc1_w, wb, NL * HD * HD / 4);
  cast_f32_bf16x4<<<64, 256, 0, stream>>>(fc2_w, wb + 65536, NL * HD * HD / 4);
  cast_f32_bf16x4<<<16, 256, 0, stream>>>(fc_w, wb + 131072, HD * HD / 4);

  int eb = (E + 255) / 256;
  const int SB = (NN + 1023) / 1024;   // 49 scan blocks
  hist_kernel<<<eb, 256, 0, stream>>>(dstp, deg, E);
  scan1_kernel<<<SB, 1024, 0, stream>>>(deg, incl, bsum, NN);
  scan2_kernel<<<1, 64, 0, stream>>>(bsum, base, off, SB, NN);
  scan3_kernel<<<SB, 1024, 0, stream>>>(deg, incl, base, off, NN);
  fill_kernel<<<eb, 256, 0, stream>>>(srcp, dstp, off, cur, csrc, E);

  const int nT = NN / 16;         // 3125 row tiles
  const int gb = (nT + 7) / 8;    // 391 blocks

  for (int i = 0; i < NL; ++i){
    agg_kernel<<<NN / 4, 256, 0, stream>>>(xb, off, csrc, hb);
    gemm_kernel<<<gb, 256, 0, stream>>>(hb, wb + i * 16384, fc1_b + i * 128,
                                        y, stats + (2 * i) * 256, nT);
    stats1_kernel<<<1, 128, 0, stream>>>(stats + (2 * i) * 256, bn1_g + i * 128,
                                         bn1_b + i * 128, params + (2 * i) * 256);
    transform_kernel<<<2048, 256, 0, stream>>>(y, params + (2 * i) * 256, hb, NN * HD / 4);
    gemm_kernel<<<gb, 256, 0, stream>>>(hb, wb + 65536 + i * 16384, fc2_b + i * 128,
                                        y, stats + (2 * i + 1) * 256, nT);
    stats23_kernel<<<1, 128, 0, stream>>>(stats + (2 * i + 1) * 256, bn2_g + i * 128,
                                          bn3_g + i * 128, bn3_b + i * 128,
                                          params + (2 * i + 1) * 256);
    transform_kernel<<<2048, 256, 0, stream>>>(y, params + (2 * i + 1) * 256, xb, NN * HD / 4);
  }

  gemm_kernel<<<gb, 256, 0, stream>>>(xb, wb + 131072, fc_b, (float*)d_out, nullptr, nT);
}

// Round 3
// 637.394 us; speedup vs baseline: 1.1658x; 1.0581x over previous
//
#include <hip/hip_runtime.h>
#include <hip/hip_bf16.h>

#define NN 50000
#define HD 128
#define NL 4
#define BN_EPS 1e-5f

typedef __attribute__((ext_vector_type(8))) short short8;
typedef __attribute__((ext_vector_type(4))) float f32x4;

__device__ inline ushort f2bf(float f){
  uint u = __float_as_uint(f);
  uint r = (u + 0x7fffu + ((u >> 16) & 1u)) >> 16;
  return (ushort)r;
}
__device__ inline float bflo(uint u){ return __uint_as_float(u << 16); }
__device__ inline float bfhi(uint u){ return __uint_as_float(u & 0xffff0000u); }

// ---------------- cast fp32 -> bf16, vectorized x4 ----------------
__global__ void cast_f32_bf16x4(const float* __restrict__ in, ushort* __restrict__ out, int n4){
  int i = blockIdx.x * blockDim.x + threadIdx.x;
  int stride = gridDim.x * blockDim.x;
  const float4* in4 = (const float4*)in;
  for (; i < n4; i += stride){
    float4 v = in4[i];
    ushort4 r;
    r.x = f2bf(v.x); r.y = f2bf(v.y); r.z = f2bf(v.z); r.w = f2bf(v.w);
    *(ushort4*)(out + i * 4) = r;
  }
}

// all three weight tensors in one launch; dest offsets are contiguous in wb
__global__ void cast_weights(const float* __restrict__ w1, const float* __restrict__ w2,
                             const float* __restrict__ wf, ushort* __restrict__ wb){
  int i = blockIdx.x * 256 + threadIdx.x;   // quad index, total 36864
  if (i >= 36864) return;
  const float* src;
  if (i < 16384)      src = w1 + i * 4;
  else if (i < 32768) src = w2 + (i - 16384) * 4;
  else                src = wf + (i - 32768) * 4;
  float4 v = *(const float4*)src;
  ushort4 r;
  r.x = f2bf(v.x); r.y = f2bf(v.y); r.z = f2bf(v.z); r.w = f2bf(v.w);
  *(ushort4*)(wb + i * 4) = r;
}

// ---------------- CSR build ----------------
__global__ void hist_kernel(const int* __restrict__ dst, int* __restrict__ deg, int E){
  int e = blockIdx.x * 256 + threadIdx.x;
  if (e < E) atomicAdd(&deg[dst[e]], 1);
}

__global__ void scan1_kernel(const int* __restrict__ deg, int* __restrict__ incl,
                             int* __restrict__ bsum, int n){
  __shared__ int tmp[1024];
  int gid = blockIdx.x * 1024 + threadIdx.x;
  int v = (gid < n) ? deg[gid] : 0;
  tmp[threadIdx.x] = v;
  __syncthreads();
  for (int ofs = 1; ofs < 1024; ofs <<= 1){
    int t = tmp[threadIdx.x];
    int a = (threadIdx.x >= ofs) ? tmp[threadIdx.x - ofs] : 0;
    __syncthreads();
    tmp[threadIdx.x] = t + a;
    __syncthreads();
  }
  if (gid < n) incl[gid] = tmp[threadIdx.x];
  if (threadIdx.x == 1023) bsum[blockIdx.x] = tmp[1023];
}

__global__ void scan2_kernel(const int* __restrict__ bsum, int* __restrict__ base,
                             int* __restrict__ off, int nb, int n){
  if (threadIdx.x == 0){
    int run = 0;
    for (int i = 0; i < nb; ++i){ base[i] = run; run += bsum[i]; }
    off[n] = run;
  }
}

__global__ void scan3_kernel(const int* __restrict__ deg, const int* __restrict__ incl,
                             const int* __restrict__ base, int* __restrict__ off, int n){
  int gid = blockIdx.x * 1024 + threadIdx.x;
  if (gid < n) off[gid] = incl[gid] - deg[gid] + base[blockIdx.x];
}

__global__ void fill_kernel(const int* __restrict__ src, const int* __restrict__ dst,
                            const int* __restrict__ off, int* __restrict__ cur,
                            int* __restrict__ csrc, int E){
  int e = blockIdx.x * 256 + threadIdx.x;
  if (e < E){
    int d = dst[e];
    int p = atomicAdd(&cur[d], 1);
    csrc[off[d] + p] = src[e];
  }
}

// ---------------- aggregation ----------------
__global__ __launch_bounds__(256) void agg_kernel(const ushort* __restrict__ xb,
                                                  const int* __restrict__ off,
                                                  const int* __restrict__ csrc,
                                                  ushort* __restrict__ h){
  int node = blockIdx.x * 4 + (threadIdx.x >> 6);
  int lane = threadIdx.x & 63;
  const uint* xr = (const uint*)xb;
  uint self = xr[node * 64 + lane];
  float ax = bflo(self), ay = bfhi(self);
  int s = off[node], e = off[node + 1];
  int j = s;
  for (; j + 4 <= e; j += 4){
    int u0 = csrc[j], u1 = csrc[j+1], u2 = csrc[j+2], u3 = csrc[j+3];
    uint v0 = xr[u0 * 64 + lane];
    uint v1 = xr[u1 * 64 + lane];
    uint v2 = xr[u2 * 64 + lane];
    uint v3 = xr[u3 * 64 + lane];
    ax += bflo(v0) + bflo(v1) + bflo(v2) + bflo(v3);
    ay += bfhi(v0) + bfhi(v1) + bfhi(v2) + bfhi(v3);
  }
  for (; j < e; ++j){
    uint v = xr[csrc[j] * 64 + lane];
    ax += bflo(v); ay += bfhi(v);
  }
  uint o = (uint)f2bf(ax) | ((uint)f2bf(ay) << 16);
  ((uint*)h)[node * 64 + lane] = o;
}

// ---------------- BN param helpers (device) ----------------
__device__ inline void bn_params(const float* st, const float* gA, const float* gB,
                                 const float* bB, int mode, float* sS, float* sT){
  int c = threadIdx.x;
  if (c < 128){
    const float invN = 1.f / (float)NN;
    float mu = st[c] * invN;
    float var = fmaxf(st[128 + c] * invN - mu * mu, 0.f);
    float S, T;
    if (mode == 0){
      S = gA[c] * rsqrtf(var + BN_EPS);
      T = gB[c] - mu * S;
    } else {
      float inv2 = rsqrtf(var + BN_EPS);
      float tt = gA[c] * inv2;
      float inv3 = rsqrtf(tt * tt * var + BN_EPS);
      S = tt * inv3 * gB[c];
      T = bB[c] - mu * S;
    }
    sS[c] = S; sT[c] = T;
  }
}

// ---------------- GEMM (A bf16): Y = A @ W^T + bias, fused column stats ----------------
__global__ __launch_bounds__(256) void gemm_kernel(const ushort* __restrict__ A,
                                                   const ushort* __restrict__ W,
                                                   const float* __restrict__ bias,
                                                   float* __restrict__ Y,
                                                   float* __restrict__ stats,
                                                   int nTiles){
  __shared__ uint4 w4[128 * 17];
  __shared__ float ssum[128];
  __shared__ float ssq[128];
  const uint4* Wg = (const uint4*)W;
  for (int c = threadIdx.x; c < 2048; c += 256){
    w4[(c >> 4) * 17 + (c & 15)] = Wg[c];
  }
  if (threadIdx.x < 128){ ssum[threadIdx.x] = 0.f; ssq[threadIdx.x] = 0.f; }
  __syncthreads();

  int wave = threadIdx.x >> 6;
  int lane = threadIdx.x & 63;
  int m = lane & 15, q = lane >> 4;
  int t0 = blockIdx.x * 8 + wave * 2;
  int t1 = t0 + 1;
  bool v0 = t0 < nTiles, v1 = t1 < nTiles;
  const uint4* A4 = (const uint4*)A;

  f32x4 acc0[8], acc1[8];
#pragma unroll
  for (int i = 0; i < 8; ++i){ acc0[i] = (f32x4)0.f; acc1[i] = (f32x4)0.f; }

#pragma unroll
  for (int kt = 0; kt < 4; ++kt){
    short8 a0 = (short8)0, a1 = (short8)0;
    if (v0){ uint4 t = A4[(t0 * 16 + m) * 16 + kt * 4 + q]; a0 = *(short8*)&t; }
    if (v1){ uint4 t = A4[(t1 * 16 + m) * 16 + kt * 4 + q]; a1 = *(short8*)&t; }
#pragma unroll
    for (int to = 0; to < 8; ++to){
      uint4 bw = w4[(to * 16 + m) * 17 + kt * 4 + q];
      short8 bb = *(short8*)&bw;
      acc0[to] = __builtin_amdgcn_mfma_f32_16x16x32_bf16(a0, bb, acc0[to], 0, 0, 0);
      acc1[to] = __builtin_amdgcn_mfma_f32_16x16x32_bf16(a1, bb, acc1[to], 0, 0, 0);
    }
  }

#pragma unroll
  for (int to = 0; to < 8; ++to){
    int col = to * 16 + m;
    float bc = bias[col];
    if (v0){
      float ls = 0.f, lq = 0.f;
#pragma unroll
      for (int r = 0; r < 4; ++r){
        float v = acc0[to][r] + bc;
        Y[(t0 * 16 + q * 4 + r) * 128 + col] = v;
        ls += v; lq += v * v;
      }
      atomicAdd(&ssum[col], ls); atomicAdd(&ssq[col], lq);
    }
    if (v1){
      float ls = 0.f, lq = 0.f;
#pragma unroll
      for (int r = 0; r < 4; ++r){
        float v = acc1[to][r] + bc;
        Y[(t1 * 16 + q * 4 + r) * 128 + col] = v;
        ls += v; lq += v * v;
      }
      atomicAdd(&ssum[col], ls); atomicAdd(&ssq[col], lq);
    }
  }
  __syncthreads();
  if (threadIdx.x < 128){
    atomicAdd(&stats[threadIdx.x], ssum[threadIdx.x]);
    atomicAdd(&stats[128 + threadIdx.x], ssq[threadIdx.x]);
  }
}

// ---------------- GEMM with BN-on-load: Y = relu(A*s+t)bf16 @ W^T + bias ----------------
// A is f32 [N,128]; params computed in prologue from statsIn. In-place A==Y is safe
// (each block reads only the rows it writes; stores depend on all its loads).
__global__ __launch_bounds__(256) void gemm_fused(const float* A,
                                                  const ushort* __restrict__ W,
                                                  const float* __restrict__ bias,
                                                  float* Y,
                                                  float* __restrict__ statsOut,
                                                  const float* __restrict__ statsIn,
                                                  const float* __restrict__ gA,
                                                  const float* __restrict__ gB,
                                                  const float* __restrict__ bB,
                                                  int mode, int nTiles){
  __shared__ uint4 w4[128 * 17];
  __shared__ float ssum[128];
  __shared__ float ssq[128];
  __shared__ __align__(16) float sS[128];
  __shared__ __align__(16) float sT[128];
  const uint4* Wg = (const uint4*)W;
  for (int c = threadIdx.x; c < 2048; c += 256){
    w4[(c >> 4) * 17 + (c & 15)] = Wg[c];
  }
  bn_params(statsIn, gA, gB, bB, mode, sS, sT);
  if (threadIdx.x < 128){ ssum[threadIdx.x] = 0.f; ssq[threadIdx.x] = 0.f; }
  __syncthreads();

  int wave = threadIdx.x >> 6;
  int lane = threadIdx.x & 63;
  int m = lane & 15, q = lane >> 4;
  int t0 = blockIdx.x * 8 + wave * 2;
  int t1 = t0 + 1;
  bool v0 = t0 < nTiles, v1 = t1 < nTiles;

  f32x4 acc0[8], acc1[8];
#pragma unroll
  for (int i = 0; i < 8; ++i){ acc0[i] = (f32x4)0.f; acc1[i] = (f32x4)0.f; }

#pragma unroll
  for (int kt = 0; kt < 4; ++kt){
    int kc = kt * 32 + q * 8;
    float4 s0 = *(const float4*)&sS[kc], s1 = *(const float4*)&sS[kc + 4];
    float4 tt0 = *(const float4*)&sT[kc], tt1 = *(const float4*)&sT[kc + 4];
    short8 a0 = (short8)0, a1 = (short8)0;
    if (v0){
      const float4* p = (const float4*)(A + (t0 * 16 + m) * 128 + kc);
      float4 u = p[0], v = p[1];
      uint4 pk;
      pk.x = (uint)f2bf(fmaxf(u.x*s0.x+tt0.x,0.f)) | ((uint)f2bf(fmaxf(u.y*s0.y+tt0.y,0.f)) << 16);
      pk.y = (uint)f2bf(fmaxf(u.z*s0.z+tt0.z,0.f)) | ((uint)f2bf(fmaxf(u.w*s0.w+tt0.w,0.f)) << 16);
      pk.z = (uint)f2bf(fmaxf(v.x*s1.x+tt1.x,0.f)) | ((uint)f2bf(fmaxf(v.y*s1.y+tt1.y,0.f)) << 16);
      pk.w = (uint)f2bf(fmaxf(v.z*s1.z+tt1.z,0.f)) | ((uint)f2bf(fmaxf(v.w*s1.w+tt1.w,0.f)) << 16);
      a0 = *(short8*)&pk;
    }
    if (v1){
      const float4* p = (const float4*)(A + (t1 * 16 + m) * 128 + kc);
      float4 u = p[0], v = p[1];
      uint4 pk;
      pk.x = (uint)f2bf(fmaxf(u.x*s0.x+tt0.x,0.f)) | ((uint)f2bf(fmaxf(u.y*s0.y+tt0.y,0.f)) << 16);
      pk.y = (uint)f2bf(fmaxf(u.z*s0.z+tt0.z,0.f)) | ((uint)f2bf(fmaxf(u.w*s0.w+tt0.w,0.f)) << 16);
      pk.z = (uint)f2bf(fmaxf(v.x*s1.x+tt1.x,0.f)) | ((uint)f2bf(fmaxf(v.y*s1.y+tt1.y,0.f)) << 16);
      pk.w = (uint)f2bf(fmaxf(v.z*s1.z+tt1.z,0.f)) | ((uint)f2bf(fmaxf(v.w*s1.w+tt1.w,0.f)) << 16);
      a1 = *(short8*)&pk;
    }
#pragma unroll
    for (int to = 0; to < 8; ++to){
      uint4 bw = w4[(to * 16 + m) * 17 + kt * 4 + q];
      short8 bb = *(short8*)&bw;
      acc0[to] = __builtin_amdgcn_mfma_f32_16x16x32_bf16(a0, bb, acc0[to], 0, 0, 0);
      acc1[to] = __builtin_amdgcn_mfma_f32_16x16x32_bf16(a1, bb, acc1[to], 0, 0, 0);
    }
  }

  bool dost = (statsOut != nullptr);
#pragma unroll
  for (int to = 0; to < 8; ++to){
    int col = to * 16 + m;
    float bc = bias[col];
    if (v0){
      float ls = 0.f, lq = 0.f;
#pragma unroll
      for (int r = 0; r < 4; ++r){
        float v = acc0[to][r] + bc;
        Y[(t0 * 16 + q * 4 + r) * 128 + col] = v;
        ls += v; lq += v * v;
      }
      if (dost){ atomicAdd(&ssum[col], ls); atomicAdd(&ssq[col], lq); }
    }
    if (v1){
      float ls = 0.f, lq = 0.f;
#pragma unroll
      for (int r = 0; r < 4; ++r){
        float v = acc1[to][r] + bc;
        Y[(t1 * 16 + q * 4 + r) * 128 + col] = v;
        ls += v; lq += v * v;
      }
      if (dost){ atomicAdd(&ssum[col], ls); atomicAdd(&ssq[col], lq); }
    }
  }
  __syncthreads();
  if (dost && threadIdx.x < 128){
    atomicAdd(&statsOut[threadIdx.x], ssum[threadIdx.x]);
    atomicAdd(&statsOut[128 + threadIdx.x], ssq[threadIdx.x]);
  }
}

// ---------------- transform: params inline (bn23), y f32 -> relu affine -> bf16 ----------------
__global__ __launch_bounds__(256) void transform_fused(const float* __restrict__ y,
                                                       const float* __restrict__ st,
                                                       const float* __restrict__ g2,
                                                       const float* __restrict__ g3,
                                                       const float* __restrict__ b3,
                                                       ushort* __restrict__ ob){
  __shared__ __align__(16) float sS[128];
  __shared__ __align__(16) float sT[128];
  bn_params(st, g2, g3, b3, 1, sS, sT);
  __syncthreads();
  const int n4 = NN * HD / 4;
  int i = blockIdx.x * 256 + threadIdx.x;
  int stride = gridDim.x * 256;
  const float4* y4 = (const float4*)y;
  for (; i < n4; i += stride){
    int col = (i * 4) & 127;
    float4 v = y4[i];
    float4 s = *(const float4*)&sS[col];
    float4 t = *(const float4*)&sT[col];
    ushort4 r;
    r.x = f2bf(fmaxf(v.x * s.x + t.x, 0.f));
    r.y = f2bf(fmaxf(v.y * s.y + t.y, 0.f));
    r.z = f2bf(fmaxf(v.z * s.z + t.z, 0.f));
    r.w = f2bf(fmaxf(v.w * s.w + t.w, 0.f));
    *(ushort4*)(ob + i * 4) = r;
  }
}

extern "C" void kernel_launch(void* const* d_in, const int* in_sizes, int n_in,
                              void* d_out, int out_size, void* d_ws, size_t ws_size,
                              hipStream_t stream) {
  const float* x     = (const float*)d_in[0];
  const int*   ei    = (const int*)d_in[1];
  const float* fc1_w = (const float*)d_in[2];
  const float* fc1_b = (const float*)d_in[3];
  const float* bn1_g = (const float*)d_in[4];
  const float* bn1_b = (const float*)d_in[5];
  const float* fc2_w = (const float*)d_in[6];
  const float* fc2_b = (const float*)d_in[7];
  const float* bn2_g = (const float*)d_in[8];
  const float* bn3_g = (const float*)d_in[10];
  const float* bn3_b = (const float*)d_in[11];
  const float* fc_w  = (const float*)d_in[12];
  const float* fc_b  = (const float*)d_in[13];

  int E = in_sizes[1] / 2;
  const int* srcp = ei;
  const int* dstp = ei + E;

  char* ws = (char*)d_ws;
  int*    off    = (int*)(ws + 0);            // (N+1) ints
  int*    deg    = (int*)(ws + 200064);       // N ints
  int*    cur    = (int*)(ws + 400128);       // N ints
  int*    csrc   = (int*)(ws + 600192);       // E ints (aliased as `incl` pre-fill)
  ushort* wb     = (ushort*)(ws + 3800192);   // 147456 bf16
  float*  stats  = (float*)(ws + 4095104);    // 8 slices x 256
  float*  params = (float*)(ws + 4103296);    // scan scratch (bsum/base)
  ushort* xb     = (ushort*)(ws + 4111488);   // N*128 bf16
  ushort* hb     = (ushort*)(ws + 16911488);  // N*128 bf16
  float*  y      = (float*)(ws + 29711488);   // N*128 f32

  int* incl = csrc;
  int* bsum = (int*)params;
  int* base = (int*)params + 64;

  hipMemsetAsync(deg, 0, 400128, stream);     // deg + cur
  hipMemsetAsync(stats, 0, 8192, stream);

  cast_f32_bf16x4<<<2048, 256, 0, stream>>>(x, xb, NN * HD / 4);
  cast_weights<<<144, 256, 0, stream>>>(fc1_w, fc2_w, fc_w, wb);

  int eb = (E + 255) / 256;
  const int SB = (NN + 1023) / 1024;
  hist_kernel<<<eb, 256, 0, stream>>>(dstp, deg, E);
  scan1_kernel<<<SB, 1024, 0, stream>>>(deg, incl, bsum, NN);
  scan2_kernel<<<1, 64, 0, stream>>>(bsum, base, off, SB, NN);
  scan3_kernel<<<SB, 1024, 0, stream>>>(deg, incl, base, off, NN);
  fill_kernel<<<eb, 256, 0, stream>>>(srcp, dstp, off, cur, csrc, E);

  const int nT = NN / 16;
  const int gb = (nT + 7) / 8;

  for (int i = 0; i < NL; ++i){
    agg_kernel<<<NN / 4, 256, 0, stream>>>(xb, off, csrc, hb);
    gemm_kernel<<<gb, 256, 0, stream>>>(hb, wb + i * 16384, fc1_b + i * 128,
                                        y, stats + (2 * i) * 256, nT);
    gemm_fused<<<gb, 256, 0, stream>>>(y, wb + 65536 + i * 16384, fc2_b + i * 128,
                                       y, stats + (2 * i + 1) * 256,
                                       stats + (2 * i) * 256,
                                       bn1_g + i * 128, bn1_b + i * 128, nullptr,
                                       0, nT);
    if (i < NL - 1){
      transform_fused<<<2048, 256, 0, stream>>>(y, stats + (2 * i + 1) * 256,
                                                bn2_g + i * 128, bn3_g + i * 128,
                                                bn3_b + i * 128, xb);
    }
  }

  // final classifier: A = relu(bn3(bn2(y_last))) applied on load
  gemm_fused<<<gb, 256, 0, stream>>>(y, wb + 131072, fc_b, (float*)d_out, nullptr,
                                     stats + 7 * 256,
                                     bn2_g + 384, bn3_g + 384, bn3_b + 384,
                                     1, nT);
}

// Round 4
// 634.574 us; speedup vs baseline: 1.1710x; 1.0044x over previous
//
#include <hip/hip_runtime.h>
#include <hip/hip_bf16.h>

#define NN 50000
#define HD 128
#define NL 4
#define BN_EPS 1e-5f
#define NSLICE 8
#define SLICEW (NN / NSLICE)   // 6250
#define ECHUNK 8192

typedef __attribute__((ext_vector_type(8))) short short8;
typedef __attribute__((ext_vector_type(4))) float f32x4;

__device__ inline ushort f2bf(float f){
  uint u = __float_as_uint(f);
  uint r = (u + 0x7fffu + ((u >> 16) & 1u)) >> 16;
  return (ushort)r;
}
__device__ inline float bflo(uint u){ return __uint_as_float(u << 16); }
__device__ inline float bfhi(uint u){ return __uint_as_float(u & 0xffff0000u); }

// ---------------- cast fp32 -> bf16, vectorized x4 ----------------
__global__ void cast_f32_bf16x4(const float* __restrict__ in, ushort* __restrict__ out, int n4){
  int i = blockIdx.x * blockDim.x + threadIdx.x;
  int stride = gridDim.x * blockDim.x;
  const float4* in4 = (const float4*)in;
  for (; i < n4; i += stride){
    float4 v = in4[i];
    ushort4 r;
    r.x = f2bf(v.x); r.y = f2bf(v.y); r.z = f2bf(v.z); r.w = f2bf(v.w);
    *(ushort4*)(out + i * 4) = r;
  }
}

__global__ void cast_weights(const float* __restrict__ w1, const float* __restrict__ w2,
                             const float* __restrict__ wf, ushort* __restrict__ wb){
  int i = blockIdx.x * 256 + threadIdx.x;
  if (i >= 36864) return;
  const float* src;
  if (i < 16384)      src = w1 + i * 4;
  else if (i < 32768) src = w2 + (i - 16384) * 4;
  else                src = wf + (i - 32768) * 4;
  float4 v = *(const float4*)src;
  ushort4 r;
  r.x = f2bf(v.x); r.y = f2bf(v.y); r.z = f2bf(v.z); r.w = f2bf(v.w);
  *(ushort4*)(wb + i * 4) = r;
}

// ---------------- CSR build, slice-partitioned (XCD-local scatter) ----------------
// block b: edge chunk (b>>3), acts only on dsts in slice (b&7). With round-robin
// workgroup->XCD dispatch, all RMW traffic to a deg/cur/csrc line stays in one XCD's L2.
__global__ __launch_bounds__(256) void hist_kernel(const int* __restrict__ dst,
                                                   int* __restrict__ deg, int E){
  int slice = blockIdx.x & (NSLICE - 1);
  int lo = slice * SLICEW, hi = lo + SLICEW;
  int base = (blockIdx.x >> 3) * ECHUNK;
  int end = base + ECHUNK < E ? base + ECHUNK : E;
  for (int e = base + threadIdx.x; e < end; e += 256){
    int d = dst[e];
    if (d >= lo && d < hi) atomicAdd(&deg[d], 1);
  }
}

__global__ void scan1_kernel(const int* __restrict__ deg, int* __restrict__ incl,
                             int* __restrict__ bsum, int n){
  __shared__ int tmp[1024];
  int gid = blockIdx.x * 1024 + threadIdx.x;
  int v = (gid < n) ? deg[gid] : 0;
  tmp[threadIdx.x] = v;
  __syncthreads();
  for (int ofs = 1; ofs < 1024; ofs <<= 1){
    int t = tmp[threadIdx.x];
    int a = (threadIdx.x >= ofs) ? tmp[threadIdx.x - ofs] : 0;
    __syncthreads();
    tmp[threadIdx.x] = t + a;
    __syncthreads();
  }
  if (gid < n) incl[gid] = tmp[threadIdx.x];
  if (threadIdx.x == 1023) bsum[blockIdx.x] = tmp[1023];
}

__global__ void scan2_kernel(const int* __restrict__ bsum, int* __restrict__ base,
                             int* __restrict__ off, int nb, int n){
  if (threadIdx.x == 0){
    int run = 0;
    for (int i = 0; i < nb; ++i){ base[i] = run; run += bsum[i]; }
    off[n] = run;
  }
}

__global__ void scan3_kernel(const int* __restrict__ deg, const int* __restrict__ incl,
                             const int* __restrict__ base, int* __restrict__ off, int n){
  int gid = blockIdx.x * 1024 + threadIdx.x;
  if (gid < n) off[gid] = incl[gid] - deg[gid] + base[blockIdx.x];
}

__global__ __launch_bounds__(256) void fill_kernel(const int* __restrict__ src,
                                                   const int* __restrict__ dst,
                                                   const int* __restrict__ off,
                                                   int* __restrict__ cur,
                                                   int* __restrict__ csrc, int E){
  int slice = blockIdx.x & (NSLICE - 1);
  int lo = slice * SLICEW, hi = lo + SLICEW;
  int base = (blockIdx.x >> 3) * ECHUNK;
  int end = base + ECHUNK < E ? base + ECHUNK : E;
  for (int e = base + threadIdx.x; e < end; e += 256){
    int d = dst[e];
    if (d >= lo && d < hi){
      int p = atomicAdd(&cur[d], 1);
      csrc[off[d] + p] = src[e];
    }
  }
}

// ---------------- aggregation ----------------
__global__ __launch_bounds__(256) void agg_kernel(const ushort* __restrict__ xb,
                                                  const int* __restrict__ off,
                                                  const int* __restrict__ csrc,
                                                  ushort* __restrict__ h){
  int node = blockIdx.x * 4 + (threadIdx.x >> 6);
  int lane = threadIdx.x & 63;
  const uint* xr = (const uint*)xb;
  uint self = xr[node * 64 + lane];
  float ax = bflo(self), ay = bfhi(self);
  int s = off[node], e = off[node + 1];
  int j = s;
  for (; j + 4 <= e; j += 4){
    int u0 = csrc[j], u1 = csrc[j+1], u2 = csrc[j+2], u3 = csrc[j+3];
    uint v0 = xr[u0 * 64 + lane];
    uint v1 = xr[u1 * 64 + lane];
    uint v2 = xr[u2 * 64 + lane];
    uint v3 = xr[u3 * 64 + lane];
    ax += bflo(v0) + bflo(v1) + bflo(v2) + bflo(v3);
    ay += bfhi(v0) + bfhi(v1) + bfhi(v2) + bfhi(v3);
  }
  for (; j < e; ++j){
    uint v = xr[csrc[j] * 64 + lane];
    ax += bflo(v); ay += bfhi(v);
  }
  uint o = (uint)f2bf(ax) | ((uint)f2bf(ay) << 16);
  ((uint*)h)[node * 64 + lane] = o;
}

// ---------------- BN param helpers (device) ----------------
__device__ inline void bn_params(const float* st, const float* gA, const float* gB,
                                 const float* bB, int mode, float* sS, float* sT){
  int c = threadIdx.x;
  if (c < 128){
    const float invN = 1.f / (float)NN;
    float mu = st[c] * invN;
    float var = fmaxf(st[128 + c] * invN - mu * mu, 0.f);
    float S, T;
    if (mode == 0){
      S = gA[c] * rsqrtf(var + BN_EPS);
      T = gB[c] - mu * S;
    } else {
      float inv2 = rsqrtf(var + BN_EPS);
      float tt = gA[c] * inv2;
      float inv3 = rsqrtf(tt * tt * var + BN_EPS);
      S = tt * inv3 * gB[c];
      T = bB[c] - mu * S;
    }
    sS[c] = S; sT[c] = T;
  }
}

// ---------------- GEMM (A bf16): Y = A @ W^T + bias, fused column stats ----------------
__global__ __launch_bounds__(256) void gemm_kernel(const ushort* __restrict__ A,
                                                   const ushort* __restrict__ W,
                                                   const float* __restrict__ bias,
                                                   float* __restrict__ Y,
                                                   float* __restrict__ stats,
                                                   int nTiles){
  __shared__ uint4 w4[128 * 17];
  __shared__ float ssum[128];
  __shared__ float ssq[128];
  const uint4* Wg = (const uint4*)W;
  for (int c = threadIdx.x; c < 2048; c += 256){
    w4[(c >> 4) * 17 + (c & 15)] = Wg[c];
  }
  if (threadIdx.x < 128){ ssum[threadIdx.x] = 0.f; ssq[threadIdx.x] = 0.f; }
  __syncthreads();

  int wave = threadIdx.x >> 6;
  int lane = threadIdx.x & 63;
  int m = lane & 15, q = lane >> 4;
  int t0 = blockIdx.x * 8 + wave * 2;
  int t1 = t0 + 1;
  bool v0 = t0 < nTiles, v1 = t1 < nTiles;
  const uint4* A4 = (const uint4*)A;

  f32x4 acc0[8], acc1[8];
#pragma unroll
  for (int i = 0; i < 8; ++i){ acc0[i] = (f32x4)0.f; acc1[i] = (f32x4)0.f; }

#pragma unroll
  for (int kt = 0; kt < 4; ++kt){
    short8 a0 = (short8)0, a1 = (short8)0;
    if (v0){ uint4 t = A4[(t0 * 16 + m) * 16 + kt * 4 + q]; a0 = *(short8*)&t; }
    if (v1){ uint4 t = A4[(t1 * 16 + m) * 16 + kt * 4 + q]; a1 = *(short8*)&t; }
#pragma unroll
    for (int to = 0; to < 8; ++to){
      uint4 bw = w4[(to * 16 + m) * 17 + kt * 4 + q];
      short8 bb = *(short8*)&bw;
      acc0[to] = __builtin_amdgcn_mfma_f32_16x16x32_bf16(a0, bb, acc0[to], 0, 0, 0);
      acc1[to] = __builtin_amdgcn_mfma_f32_16x16x32_bf16(a1, bb, acc1[to], 0, 0, 0);
    }
  }

#pragma unroll
  for (int to = 0; to < 8; ++to){
    int col = to * 16 + m;
    float bc = bias[col];
    if (v0){
      float ls = 0.f, lq = 0.f;
#pragma unroll
      for (int r = 0; r < 4; ++r){
        float v = acc0[to][r] + bc;
        Y[(t0 * 16 + q * 4 + r) * 128 + col] = v;
        ls += v; lq += v * v;
      }
      atomicAdd(&ssum[col], ls); atomicAdd(&ssq[col], lq);
    }
    if (v1){
      float ls = 0.f, lq = 0.f;
#pragma unroll
      for (int r = 0; r < 4; ++r){
        float v = acc1[to][r] + bc;
        Y[(t1 * 16 + q * 4 + r) * 128 + col] = v;
        ls += v; lq += v * v;
      }
      atomicAdd(&ssum[col], ls); atomicAdd(&ssq[col], lq);
    }
  }
  __syncthreads();
  if (threadIdx.x < 128){
    atomicAdd(&stats[threadIdx.x], ssum[threadIdx.x]);
    atomicAdd(&stats[128 + threadIdx.x], ssq[threadIdx.x]);
  }
}

// ---------------- GEMM with BN-on-load: Y = relu(A*s+t)bf16 @ W^T + bias ----------------
__global__ __launch_bounds__(256) void gemm_fused(const float* A,
                                                  const ushort* __restrict__ W,
                                                  const float* __restrict__ bias,
                                                  float* Y,
                                                  float* __restrict__ statsOut,
                                                  const float* __restrict__ statsIn,
                                                  const float* __restrict__ gA,
                                                  const float* __restrict__ gB,
                                                  const float* __restrict__ bB,
                                                  int mode, int nTiles){
  __shared__ uint4 w4[128 * 17];
  __shared__ float ssum[128];
  __shared__ float ssq[128];
  __shared__ __align__(16) float sS[128];
  __shared__ __align__(16) float sT[128];
  const uint4* Wg = (const uint4*)W;
  for (int c = threadIdx.x; c < 2048; c += 256){
    w4[(c >> 4) * 17 + (c & 15)] = Wg[c];
  }
  bn_params(statsIn, gA, gB, bB, mode, sS, sT);
  if (threadIdx.x < 128){ ssum[threadIdx.x] = 0.f; ssq[threadIdx.x] = 0.f; }
  __syncthreads();

  int wave = threadIdx.x >> 6;
  int lane = threadIdx.x & 63;
  int m = lane & 15, q = lane >> 4;
  int t0 = blockIdx.x * 8 + wave * 2;
  int t1 = t0 + 1;
  bool v0 = t0 < nTiles, v1 = t1 < nTiles;

  f32x4 acc0[8], acc1[8];
#pragma unroll
  for (int i = 0; i < 8; ++i){ acc0[i] = (f32x4)0.f; acc1[i] = (f32x4)0.f; }

#pragma unroll
  for (int kt = 0; kt < 4; ++kt){
    int kc = kt * 32 + q * 8;
    float4 s0 = *(const float4*)&sS[kc], s1 = *(const float4*)&sS[kc + 4];
    float4 tt0 = *(const float4*)&sT[kc], tt1 = *(const float4*)&sT[kc + 4];
    short8 a0 = (short8)0, a1 = (short8)0;
    if (v0){
      const float4* p = (const float4*)(A + (t0 * 16 + m) * 128 + kc);
      float4 u = p[0], v = p[1];
      uint4 pk;
      pk.x = (uint)f2bf(fmaxf(u.x*s0.x+tt0.x,0.f)) | ((uint)f2bf(fmaxf(u.y*s0.y+tt0.y,0.f)) << 16);
      pk.y = (uint)f2bf(fmaxf(u.z*s0.z+tt0.z,0.f)) | ((uint)f2bf(fmaxf(u.w*s0.w+tt0.w,0.f)) << 16);
      pk.z = (uint)f2bf(fmaxf(v.x*s1.x+tt1.x,0.f)) | ((uint)f2bf(fmaxf(v.y*s1.y+tt1.y,0.f)) << 16);
      pk.w = (uint)f2bf(fmaxf(v.z*s1.z+tt1.z,0.f)) | ((uint)f2bf(fmaxf(v.w*s1.w+tt1.w,0.f)) << 16);
      a0 = *(short8*)&pk;
    }
    if (v1){
      const float4* p = (const float4*)(A + (t1 * 16 + m) * 128 + kc);
      float4 u = p[0], v = p[1];
      uint4 pk;
      pk.x = (uint)f2bf(fmaxf(u.x*s0.x+tt0.x,0.f)) | ((uint)f2bf(fmaxf(u.y*s0.y+tt0.y,0.f)) << 16);
      pk.y = (uint)f2bf(fmaxf(u.z*s0.z+tt0.z,0.f)) | ((uint)f2bf(fmaxf(u.w*s0.w+tt0.w,0.f)) << 16);
      pk.z = (uint)f2bf(fmaxf(v.x*s1.x+tt1.x,0.f)) | ((uint)f2bf(fmaxf(v.y*s1.y+tt1.y,0.f)) << 16);
      pk.w = (uint)f2bf(fmaxf(v.z*s1.z+tt1.z,0.f)) | ((uint)f2bf(fmaxf(v.w*s1.w+tt1.w,0.f)) << 16);
      a1 = *(short8*)&pk;
    }
#pragma unroll
    for (int to = 0; to < 8; ++to){
      uint4 bw = w4[(to * 16 + m) * 17 + kt * 4 + q];
      short8 bb = *(short8*)&bw;
      acc0[to] = __builtin_amdgcn_mfma_f32_16x16x32_bf16(a0, bb, acc0[to], 0, 0, 0);
      acc1[to] = __builtin_amdgcn_mfma_f32_16x16x32_bf16(a1, bb, acc1[to], 0, 0, 0);
    }
  }

  bool dost = (statsOut != nullptr);
#pragma unroll
  for (int to = 0; to < 8; ++to){
    int col = to * 16 + m;
    float bc = bias[col];
    if (v0){
      float ls = 0.f, lq = 0.f;
#pragma unroll
      for (int r = 0; r < 4; ++r){
        float v = acc0[to][r] + bc;
        Y[(t0 * 16 + q * 4 + r) * 128 + col] = v;
        ls += v; lq += v * v;
      }
      if (dost){ atomicAdd(&ssum[col], ls); atomicAdd(&ssq[col], lq); }
    }
    if (v1){
      float ls = 0.f, lq = 0.f;
#pragma unroll
      for (int r = 0; r < 4; ++r){
        float v = acc1[to][r] + bc;
        Y[(t1 * 16 + q * 4 + r) * 128 + col] = v;
        ls += v; lq += v * v;
      }
      if (dost){ atomicAdd(&ssum[col], ls); atomicAdd(&ssq[col], lq); }
    }
  }
  __syncthreads();
  if (dost && threadIdx.x < 128){
    atomicAdd(&statsOut[threadIdx.x], ssum[threadIdx.x]);
    atomicAdd(&statsOut[128 + threadIdx.x], ssq[threadIdx.x]);
  }
}

// ---------------- transform: params inline (bn23), y f32 -> relu affine -> bf16 ----------------
__global__ __launch_bounds__(256) void transform_fused(const float* __restrict__ y,
                                                       const float* __restrict__ st,
                                                       const float* __restrict__ g2,
                                                       const float* __restrict__ g3,
                                                       const float* __restrict__ b3,
                                                       ushort* __restrict__ ob){
  __shared__ __align__(16) float sS[128];
  __shared__ __align__(16) float sT[128];
  bn_params(st, g2, g3, b3, 1, sS, sT);
  __syncthreads();
  const int n4 = NN * HD / 4;
  int i = blockIdx.x * 256 + threadIdx.x;
  int stride = gridDim.x * 256;
  const float4* y4 = (const float4*)y;
  for (; i < n4; i += stride){
    int col = (i * 4) & 127;
    float4 v = y4[i];
    float4 s = *(const float4*)&sS[col];
    float4 t = *(const float4*)&sT[col];
    ushort4 r;
    r.x = f2bf(fmaxf(v.x * s.x + t.x, 0.f));
    r.y = f2bf(fmaxf(v.y * s.y + t.y, 0.f));
    r.z = f2bf(fmaxf(v.z * s.z + t.z, 0.f));
    r.w = f2bf(fmaxf(v.w * s.w + t.w, 0.f));
    *(ushort4*)(ob + i * 4) = r;
  }
}

extern "C" void kernel_launch(void* const* d_in, const int* in_sizes, int n_in,
                              void* d_out, int out_size, void* d_ws, size_t ws_size,
                              hipStream_t stream) {
  const float* x     = (const float*)d_in[0];
  const int*   ei    = (const int*)d_in[1];
  const float* fc1_w = (const float*)d_in[2];
  const float* fc1_b = (const float*)d_in[3];
  const float* bn1_g = (const float*)d_in[4];
  const float* bn1_b = (const float*)d_in[5];
  const float* fc2_w = (const float*)d_in[6];
  const float* fc2_b = (const float*)d_in[7];
  const float* bn2_g = (const float*)d_in[8];
  const float* bn3_g = (const float*)d_in[10];
  const float* bn3_b = (const float*)d_in[11];
  const float* fc_w  = (const float*)d_in[12];
  const float* fc_b  = (const float*)d_in[13];

  int E = in_sizes[1] / 2;
  const int* srcp = ei;
  const int* dstp = ei + E;

  char* ws = (char*)d_ws;
  int*    off    = (int*)(ws + 0);            // (N+1) ints
  int*    deg    = (int*)(ws + 200064);       // N ints
  int*    cur    = (int*)(ws + 400128);       // N ints
  int*    csrc   = (int*)(ws + 600192);       // E ints (aliased as `incl` pre-fill)
  ushort* wb     = (ushort*)(ws + 3800192);   // 147456 bf16
  float*  stats  = (float*)(ws + 4095104);    // 8 slices x 256
  float*  params = (float*)(ws + 4103296);    // scan scratch (bsum/base)
  ushort* xb     = (ushort*)(ws + 4111488);   // N*128 bf16
  ushort* hb     = (ushort*)(ws + 16911488);  // N*128 bf16
  float*  y      = (float*)(ws + 29711488);   // N*128 f32

  int* incl = csrc;
  int* bsum = (int*)params;
  int* base = (int*)params + 64;

  hipMemsetAsync(deg, 0, 400128, stream);     // deg + cur
  hipMemsetAsync(stats, 0, 8192, stream);

  cast_f32_bf16x4<<<2048, 256, 0, stream>>>(x, xb, NN * HD / 4);
  cast_weights<<<144, 256, 0, stream>>>(fc1_w, fc2_w, fc_w, wb);

  const int SB = (NN + 1023) / 1024;
  const int chunks = (E + ECHUNK - 1) / ECHUNK;
  hist_kernel<<<chunks * NSLICE, 256, 0, stream>>>(dstp, deg, E);
  scan1_kernel<<<SB, 1024, 0, stream>>>(deg, incl, bsum, NN);
  scan2_kernel<<<1, 64, 0, stream>>>(bsum, base, off, SB, NN);
  scan3_kernel<<<SB, 1024, 0, stream>>>(deg, incl, base, off, NN);
  fill_kernel<<<chunks * NSLICE, 256, 0, stream>>>(srcp, dstp, off, cur, csrc, E);

  const int nT = NN / 16;
  const int gb = (nT + 7) / 8;

  for (int i = 0; i < NL; ++i){
    agg_kernel<<<NN / 4, 256, 0, stream>>>(xb, off, csrc, hb);
    gemm_kernel<<<gb, 256, 0, stream>>>(hb, wb + i * 16384, fc1_b + i * 128,
                                        y, stats + (2 * i) * 256, nT);
    gemm_fused<<<gb, 256, 0, stream>>>(y, wb + 65536 + i * 16384, fc2_b + i * 128,
                                       y, stats + (2 * i + 1) * 256,
                                       stats + (2 * i) * 256,
                                       bn1_g + i * 128, bn1_b + i * 128, nullptr,
                                       0, nT);
    if (i < NL - 1){
      transform_fused<<<2048, 256, 0, stream>>>(y, stats + (2 * i + 1) * 256,
                                                bn2_g + i * 128, bn3_g + i * 128,
                                                bn3_b + i * 128, xb);
    }
  }

  gemm_fused<<<gb, 256, 0, stream>>>(y, wb + 131072, fc_b, (float*)d_out, nullptr,
                                     stats + 7 * 256,
                                     bn2_g + 384, bn3_g + 384, bn3_b + 384,
                                     1, nT);
}